// Round 5
// baseline (114.803 us; speedup 1.0000x reference)
//
#include <hip/hip_runtime.h>
#include <hip/hip_bf16.h>

#define NN 100000
#define DEG 16
#define NF 128
#define HID 128
#define NC 16
#define NB 10000

typedef float f32x16 __attribute__((ext_vector_type(16)));
typedef short s16x8 __attribute__((ext_vector_type(8)));

__device__ __forceinline__ ushort f2bf(float f) {   // RNE (prep kernel only)
    unsigned u = __builtin_bit_cast(unsigned, f);
    return (ushort)((u + 0x7FFFu + ((u >> 16) & 1u)) >> 16);
}
__device__ __forceinline__ float bf2f(ushort h) {
    return __builtin_bit_cast(float, (unsigned)h << 16);
}
// HW packed fp32->bf16 RNE: dst = {lo: cvt(a), hi: cvt(b)}
__device__ __forceinline__ uint cvtpk(float a, float b) {
    uint r;
    asm("v_cvt_pk_bf16_f32 %0, %1, %2" : "=v"(r) : "v"(a), "v"(b));
    return r;
}
__device__ __forceinline__ s16x8 pack8(float4 a, float4 b) {
    uint4 u;
    u.x = cvtpk(a.x, a.y);
    u.y = cvtpk(a.z, a.w);
    u.z = cvtpk(b.x, b.y);
    u.w = cvtpk(b.z, b.w);
    return __builtin_bit_cast(s16x8, u);
}
// XOR swizzle within a 256B LDS row: 16 slots of 16B (T2, conflict-free b128)
__device__ __forceinline__ int swz16(int row, int bo) {
    return row * 256 + (bo ^ ((row & 15) << 4));
}

// ---------------------------------------------------------------------------
// Prep: W1 -> bf16 MFMA B-fragments WFh; W2 -> WF2.
// WFh frag (c,kk): lane l holds Wb[c*32+(l&31)][kk*16+(l>>5)*8 .. +8]
//   Wb[j][k] = j<128 ? W1[j][k] : W1[j-128][128+k]
// WF2 frag (kk):   lane l holds W2b[(l&31)][kk*16+(l>>5)*8 .. +8]
//   W2b[j][k] = j<16 ? W2[j][k] : W2[j-16][128+k]
// ---------------------------------------------------------------------------
__global__ __launch_bounds__(256)
void wf_prep(const float* __restrict__ W1, const float* __restrict__ W2,
             ushort* __restrict__ WFh, ushort* __restrict__ WF2) {
    const int t = blockIdx.x * 256 + threadIdx.x;
    if (t >= 72 * 64) return;
    const int frag = t >> 6;
    const int lane = t & 63;
    const int k0 = (frag & 7) * 16 + (lane >> 5) * 8;

    if (frag < 64) {
        const int vcol = (frag >> 3) * 32 + (lane & 31);
        const float* src = (vcol < 128) ? W1 + (size_t)vcol * 256
                                        : W1 + (size_t)(vcol - 128) * 256 + 128;
        ushort hh[8];
        #pragma unroll
        for (int j = 0; j < 8; ++j) hh[j] = f2bf(src[k0 + j]);
        *(uint4*)(WFh + (size_t)t * 8) = *(const uint4*)hh;
    } else {
        const int vcol = lane & 31;
        const float* src = (vcol < 16) ? W2 + (size_t)vcol * 256
                                       : W2 + (size_t)(vcol - 16) * 256 + 128;
        ushort hh[8];
        #pragma unroll
        for (int j = 0; j < 8; ++j) hh[j] = f2bf(src[k0 + j]);
        *(uint4*)(WF2 + (size_t)((frag - 64) * 64 + lane) * 8) = *(const uint4*)hh;
    }
}

// ---------------------------------------------------------------------------
// GEMM1 (no LDS): tile = 128 rows x 128 cols (ct selects col half), K=128.
// 4 waves: wm = row half (2x32 frags), wn = col half of 64 (2x32 frags).
// Bijective XCD swizzle pairs the two ct-blocks of a row tile on one XCD.
// ---------------------------------------------------------------------------
__global__ __launch_bounds__(256, 3)
void gemm1(const float* __restrict__ X, const ushort* __restrict__ WFh,
           ushort* __restrict__ Qb, ushort* __restrict__ Pb) {
    const int orig = blockIdx.x;               // 1564 wgs
    const int qq = 1564 / 8, rr = 1564 % 8;
    const int xcd = orig & 7, pos = orig >> 3;
    const int wgid = (xcd < rr ? xcd * (qq + 1) : rr * (qq + 1) + (xcd - rr) * qq) + pos;
    const int bx = wgid >> 1;
    const int ct = wgid & 1;
    const int row0 = bx * 128;

    const int t = threadIdx.x;
    const int lane = t & 63;
    const int w = t >> 6;
    const int wm = w >> 1, wn = w & 1;

    int r0 = row0 + wm * 64 + (lane & 31);
    int r1 = r0 + 32;
    if (r0 > NN - 1) r0 = NN - 1;
    if (r1 > NN - 1) r1 = NN - 1;
    const float* a0p = X + (size_t)r0 * NF + (lane >> 5) * 8;
    const float* a1p = X + (size_t)r1 * NF + (lane >> 5) * 8;

    f32x16 acc[2][2];
    #pragma unroll
    for (int m = 0; m < 2; ++m)
        #pragma unroll
        for (int n = 0; n < 2; ++n)
            acc[m][n] = (f32x16){0,0,0,0,0,0,0,0,0,0,0,0,0,0,0,0};

    #pragma unroll
    for (int kk = 0; kk < 8; ++kk) {
        const s16x8 a0h = pack8(*(const float4*)(a0p + kk * 16),
                                *(const float4*)(a0p + kk * 16 + 4));
        const s16x8 a1h = pack8(*(const float4*)(a1p + kk * 16),
                                *(const float4*)(a1p + kk * 16 + 4));
        #pragma unroll
        for (int n = 0; n < 2; ++n) {
            const int cf = ct * 4 + wn * 2 + n;
            const size_t fo = (size_t)((cf * 8 + kk) * 64 + lane) * 8;
            const s16x8 bh = *(const s16x8*)(WFh + fo);
            acc[0][n] = __builtin_amdgcn_mfma_f32_32x32x16_bf16(a0h, bh, acc[0][n], 0, 0, 0);
            acc[1][n] = __builtin_amdgcn_mfma_f32_32x32x16_bf16(a1h, bh, acc[1][n], 0, 0, 0);
        }
    }

    // C/D layout: col=lane&31, row=(g&3)+8*(g>>2)+4*(lane>>5)
    ushort* OUT = ct ? Pb : Qb;
    const int ccol = lane & 31;
    const int crow4 = 4 * (lane >> 5);
    #pragma unroll
    for (int m = 0; m < 2; ++m) {
        #pragma unroll
        for (int n = 0; n < 2; ++n) {
            const int col = wn * 64 + n * 32 + ccol;
            #pragma unroll
            for (int g = 0; g < 16; g += 2) {
                const uint pk = cvtpk(acc[m][n][g], acc[m][n][g + 1]);
                const int row = row0 + wm * 64 + m * 32 + (g & 3) + 8 * (g >> 2) + crow4;
                if (row < NN)     OUT[(size_t)row * HID + col] = (ushort)pk;
                if (row + 1 < NN) OUT[(size_t)(row + 1) * HID + col] = (ushort)(pk >> 16);
            }
        }
    }
}

// ---------------------------------------------------------------------------
// Fused aggregate + GEMM2. Block = 128 nodes, 32KB LDS (4 blocks/CU).
// Phase A: h1[n] = relu(Qb[n] + mean_d Pb[nbr(n,d)]) -> swizzled LDS (bf16).
// Phase B: ST = h1 @ W2frag (MFMA from LDS) -> STb (bf16).
// ---------------------------------------------------------------------------
__global__ __launch_bounds__(256, 4)
void agg_gemm2(const int* __restrict__ nidx, const ushort* __restrict__ Pb,
               const ushort* __restrict__ Qb, const ushort* __restrict__ WF2,
               ushort* __restrict__ STb) {
    __shared__ char hs[128 * 256];  // 32KB: 128 rows x 128 bf16, swizzled
    const int t = threadIdx.x;
    const int node0 = blockIdx.x * 128;
    const int sl = t & 15;   // 16B slice of a row
    const int ng = t >> 4;   // node slot 0..15

    const float inv = 1.0f / 16.0f;
    #pragma unroll 1
    for (int it = 0; it < 8; ++it) {
        const int r = ng + it * 16;          // local row 0..127
        int node = node0 + r;
        if (node > NN - 1) node = NN - 1;
        const int myn = nidx[(size_t)node * DEG + sl];
        const s16x8 q = *(const s16x8*)(Qb + (size_t)node * HID + sl * 8);
        uint off[16];
        #pragma unroll
        for (int d = 0; d < 16; ++d)
            off[d] = (uint)__shfl(myn, d, 16) * 256u + (uint)sl * 16u;
        float s[8] = {0, 0, 0, 0, 0, 0, 0, 0};
        #pragma unroll
        for (int d = 0; d < 16; ++d) {
            const s16x8 v = *(const s16x8*)((const char*)Pb + off[d]);
            #pragma unroll
            for (int j = 0; j < 8; ++j) s[j] += bf2f((ushort)v[j]);
        }
        float h[8];
        #pragma unroll
        for (int j = 0; j < 8; ++j)
            h[j] = fmaxf(fmaf(s[j], inv, bf2f((ushort)q[j])), 0.f);
        uint4 u;
        u.x = cvtpk(h[0], h[1]);
        u.y = cvtpk(h[2], h[3]);
        u.z = cvtpk(h[4], h[5]);
        u.w = cvtpk(h[6], h[7]);
        *(uint4*)(hs + swz16(r, sl * 16)) = u;
    }
    __syncthreads();

    // Phase B: 4 waves; wave w -> local rows w*32 .. w*32+31 (1 frag)
    const int lane = t & 63;
    const int w = t >> 6;
    const int rl = w * 32;

    f32x16 acc = {0,0,0,0,0,0,0,0,0,0,0,0,0,0,0,0};
    #pragma unroll
    for (int kk = 0; kk < 8; ++kk) {
        const int kb = kk * 32 + (lane >> 5) * 16;
        const s16x8 a = *(const s16x8*)(hs + swz16(rl + (lane & 31), kb));
        const s16x8 b = *(const s16x8*)(WF2 + (size_t)(kk * 64 + lane) * 8);
        acc = __builtin_amdgcn_mfma_f32_32x32x16_bf16(a, b, acc, 0, 0, 0);
    }

    const int col = lane & 31;
    const int crow4 = 4 * (lane >> 5);
    #pragma unroll
    for (int g = 0; g < 16; g += 2) {
        const uint pk = cvtpk(acc[g], acc[g + 1]);
        const int row = node0 + rl + (g & 3) + 8 * (g >> 2) + crow4;
        if (row < NN)     STb[(size_t)row * 32 + col] = (ushort)pk;
        if (row + 1 < NN) STb[(size_t)(row + 1) * 32 + col] = (ushort)(pk >> 16);
    }
}

// ---------------------------------------------------------------------------
// Final: out[b][j] = S[node_b][j] + (1/16)*sum_d T[nbr(node_b,d)][j]
// One thread per (b, col-pair): dword gathers, float2 stores.
// ---------------------------------------------------------------------------
__global__ __launch_bounds__(256)
void final_out(const int* __restrict__ nodes, const int* __restrict__ nidx,
               const ushort* __restrict__ STb, float* __restrict__ out) {
    const int g = blockIdx.x * 256 + threadIdx.x;
    if (g >= NB * NC / 2) return;
    const int b = g >> 3;
    const int jp = g & 7;
    const int node = nodes[b];
    const uint sv = *(const uint*)(STb + (size_t)node * 32 + jp * 2);
    const int* nb = nidx + (size_t)node * DEG;
    float a0 = 0.f, a1 = 0.f;
    #pragma unroll
    for (int d = 0; d < DEG; ++d) {
        const uint v = *(const uint*)(STb + (size_t)nb[d] * 32 + 16 + jp * 2);
        a0 += bf2f((ushort)v);
        a1 += bf2f((ushort)(v >> 16));
    }
    float2 o;
    o.x = fmaf(a0, 1.0f / 16.0f, bf2f((ushort)sv));
    o.y = fmaf(a1, 1.0f / 16.0f, bf2f((ushort)(sv >> 16)));
    *(float2*)(out + (size_t)b * 16 + jp * 2) = o;
}

extern "C" void kernel_launch(void* const* d_in, const int* in_sizes, int n_in,
                              void* d_out, int out_size, void* d_ws, size_t ws_size,
                              hipStream_t stream) {
    const int* nodes = (const int*)d_in[0];
    const int* nidx  = (const int*)d_in[1];
    const float* X   = (const float*)d_in[2];
    const float* W1  = (const float*)d_in[3];
    const float* W2  = (const float*)d_in[4];
    float* out = (float*)d_out;

    // ws: Qb 25.6MB | Pb 25.6MB | STb 6.4MB | WFh 64KB | WF2 8KB
    ushort* Qb  = (ushort*)d_ws;
    ushort* Pb  = Qb + (size_t)NN * HID;
    ushort* STb = Pb + (size_t)NN * HID;
    ushort* WFh = STb + (size_t)NN * 32;
    ushort* WF2 = WFh + 64 * 64 * 8;

    wf_prep<<<18, 256, 0, stream>>>(W1, W2, WFh, WF2);
    gemm1<<<1564, 256, 0, stream>>>(X, WFh, Qb, Pb);
    agg_gemm2<<<782, 256, 0, stream>>>(nidx, Pb, Qb, WF2, STb);
    final_out<<<313, 256, 0, stream>>>(nodes, nidx, STb, out);
}

// Round 6
// 91.883 us; speedup vs baseline: 1.2494x; 1.2494x over previous
//
#include <hip/hip_runtime.h>
#include <hip/hip_bf16.h>

#define NN 100000
#define DEG 16
#define NF 128
#define HID 128
#define NC 16
#define NB 10000

typedef float f32x16 __attribute__((ext_vector_type(16)));
typedef short s16x8 __attribute__((ext_vector_type(8)));

__device__ __forceinline__ ushort f2bf(float f) {   // RNE (prep kernel only)
    unsigned u = __builtin_bit_cast(unsigned, f);
    return (ushort)((u + 0x7FFFu + ((u >> 16) & 1u)) >> 16);
}
__device__ __forceinline__ float bf2f(ushort h) {
    return __builtin_bit_cast(float, (unsigned)h << 16);
}
// HW packed fp32->bf16 RNE: dst = {lo: cvt(a), hi: cvt(b)}
__device__ __forceinline__ uint cvtpk(float a, float b) {
    uint r;
    asm("v_cvt_pk_bf16_f32 %0, %1, %2" : "=v"(r) : "v"(a), "v"(b));
    return r;
}
__device__ __forceinline__ s16x8 pack8(float4 a, float4 b) {
    uint4 u;
    u.x = cvtpk(a.x, a.y);
    u.y = cvtpk(a.z, a.w);
    u.z = cvtpk(b.x, b.y);
    u.w = cvtpk(b.z, b.w);
    return __builtin_bit_cast(s16x8, u);
}
// XOR swizzle within a 256B LDS row: 16 slots of 16B (T2, conflict-free b128)
__device__ __forceinline__ int swz16(int row, int bo) {
    return row * 256 + (bo ^ ((row & 15) << 4));
}

// ---------------------------------------------------------------------------
// Prep: W1 -> bf16 MFMA B-fragments WFh; W2 -> WF2.
// WFh frag (c,kk): lane l holds Wb[c*32+(l&31)][kk*16+(l>>5)*8 .. +8]
//   Wb[j][k] = j<128 ? W1[j][k] : W1[j-128][128+k]
// WF2 frag (kk):   lane l holds W2b[(l&31)][kk*16+(l>>5)*8 .. +8]
// ---------------------------------------------------------------------------
__global__ __launch_bounds__(256)
void wf_prep(const float* __restrict__ W1, const float* __restrict__ W2,
             ushort* __restrict__ WFh, ushort* __restrict__ WF2) {
    const int t = blockIdx.x * 256 + threadIdx.x;
    if (t >= 72 * 64) return;
    const int frag = t >> 6;
    const int lane = t & 63;
    const int k0 = (frag & 7) * 16 + (lane >> 5) * 8;

    if (frag < 64) {
        const int vcol = (frag >> 3) * 32 + (lane & 31);
        const float* src = (vcol < 128) ? W1 + (size_t)vcol * 256
                                        : W1 + (size_t)(vcol - 128) * 256 + 128;
        ushort hh[8];
        #pragma unroll
        for (int j = 0; j < 8; ++j) hh[j] = f2bf(src[k0 + j]);
        *(uint4*)(WFh + (size_t)t * 8) = *(const uint4*)hh;
    } else {
        const int vcol = lane & 31;
        const float* src = (vcol < 16) ? W2 + (size_t)vcol * 256
                                       : W2 + (size_t)(vcol - 16) * 256 + 128;
        ushort hh[8];
        #pragma unroll
        for (int j = 0; j < 8; ++j) hh[j] = f2bf(src[k0 + j]);
        *(uint4*)(WF2 + (size_t)((frag - 64) * 64 + lane) * 8) = *(const uint4*)hh;
    }
}

// ---------------------------------------------------------------------------
// GEMM1 (no LDS, r4 shape): block = 128 rows x 256 cols, K=128.
// 4 waves: wm = row half, wn = col half. A from global fp32 (pack8->bf16),
// B from WFh (L2-hot). Out: cols<128 -> Qb (bf16), cols>=128 -> Pf (fp8 e4m3).
// ---------------------------------------------------------------------------
__global__ __launch_bounds__(256, 2)
void gemm1(const float* __restrict__ X, const ushort* __restrict__ WFh,
           ushort* __restrict__ Qb, unsigned char* __restrict__ Pf) {
    const int t = threadIdx.x;
    const int lane = t & 63;
    const int w = t >> 6;
    const int wm = w >> 1, wn = w & 1;
    const int row0 = blockIdx.x * 128;

    int r0 = row0 + wm * 64 + (lane & 31);
    int r1 = r0 + 32;
    if (r0 > NN - 1) r0 = NN - 1;
    if (r1 > NN - 1) r1 = NN - 1;
    const float* a0p = X + (size_t)r0 * NF + (lane >> 5) * 8;
    const float* a1p = X + (size_t)r1 * NF + (lane >> 5) * 8;

    f32x16 acc[2][4];
    #pragma unroll
    for (int m = 0; m < 2; ++m)
        #pragma unroll
        for (int n = 0; n < 4; ++n)
            acc[m][n] = (f32x16){0,0,0,0,0,0,0,0,0,0,0,0,0,0,0,0};

    #pragma unroll
    for (int kk = 0; kk < 8; ++kk) {
        const s16x8 a0h = pack8(*(const float4*)(a0p + kk * 16),
                                *(const float4*)(a0p + kk * 16 + 4));
        const s16x8 a1h = pack8(*(const float4*)(a1p + kk * 16),
                                *(const float4*)(a1p + kk * 16 + 4));
        #pragma unroll
        for (int n = 0; n < 4; ++n) {
            const size_t fo = (size_t)(((wn * 4 + n) * 8 + kk) * 64 + lane) * 8;
            const s16x8 bh = *(const s16x8*)(WFh + fo);
            acc[0][n] = __builtin_amdgcn_mfma_f32_32x32x16_bf16(a0h, bh, acc[0][n], 0, 0, 0);
            acc[1][n] = __builtin_amdgcn_mfma_f32_32x32x16_bf16(a1h, bh, acc[1][n], 0, 0, 0);
        }
    }

    // C/D layout: col=lane&31, row=(g&3)+8*(g>>2)+4*(lane>>5)
    const int ccol = lane & 31;
    const int crow4 = 4 * (lane >> 5);
    #pragma unroll
    for (int m = 0; m < 2; ++m) {
        #pragma unroll
        for (int n = 0; n < 4; ++n) {
            const int col = wn * 128 + n * 32 + ccol;
            if (col < 128) {
                #pragma unroll
                for (int g = 0; g < 16; g += 2) {
                    const uint pk = cvtpk(acc[m][n][g], acc[m][n][g + 1]);
                    const int row = row0 + wm * 64 + m * 32 + (g & 3) + 8 * (g >> 2) + crow4;
                    if (row < NN)     Qb[(size_t)row * HID + col] = (ushort)pk;
                    if (row + 1 < NN) Qb[(size_t)(row + 1) * HID + col] = (ushort)(pk >> 16);
                }
            } else {
                const int pc = col - 128;
                #pragma unroll
                for (int g = 0; g < 16; g += 2) {
                    const uint pk = __builtin_amdgcn_cvt_pk_fp8_f32(
                        acc[m][n][g], acc[m][n][g + 1], 0, false);
                    const int row = row0 + wm * 64 + m * 32 + (g & 3) + 8 * (g >> 2) + crow4;
                    if (row < NN)     Pf[(size_t)row * HID + pc] = (unsigned char)(pk & 0xff);
                    if (row + 1 < NN) Pf[(size_t)(row + 1) * HID + pc] = (unsigned char)((pk >> 8) & 0xff);
                }
            }
        }
    }
}

// ---------------------------------------------------------------------------
// Fused aggregate + GEMM2. Block = 128 nodes, 32KB LDS.
// Phase A: h1[n] = relu(Qb[n] + mean_d Pf[nbr(n,d)]) -> swizzled LDS (bf16).
//   Pf is fp8: 16 lanes/node, 8B (8 fp8) per lane per neighbor row.
//   All 16 gathers issued before decode (sched_barrier fence) for max MLP.
// Phase B: ST = h1 @ W2frag (MFMA from LDS) -> STb (bf16).
// ---------------------------------------------------------------------------
__global__ __launch_bounds__(256, 2)
void agg_gemm2(const int* __restrict__ nidx, const unsigned char* __restrict__ Pf,
               const ushort* __restrict__ Qb, const ushort* __restrict__ WF2,
               ushort* __restrict__ STb) {
    __shared__ char hs[128 * 256];  // 32KB: 128 rows x 128 bf16, swizzled
    const int t = threadIdx.x;
    const int node0 = blockIdx.x * 128;
    const int sl = t & 15;   // 8B fp8-slice of a row
    const int ng = t >> 4;   // node slot 0..15

    const float inv = 1.0f / 16.0f;
    #pragma unroll 1
    for (int it = 0; it < 8; ++it) {
        const int r = ng + it * 16;          // local row 0..127
        int node = node0 + r;
        if (node > NN - 1) node = NN - 1;
        const int myn = nidx[(size_t)node * DEG + sl];
        const s16x8 q = *(const s16x8*)(Qb + (size_t)node * HID + sl * 8);

        uint2 vv[16];
        #pragma unroll
        for (int d = 0; d < 16; ++d) {
            const uint id = (uint)__shfl(myn, d, 16);
            vv[d] = *(const uint2*)(Pf + (size_t)id * HID + sl * 8);
        }
        __builtin_amdgcn_sched_barrier(0);   // all 16 gathers in flight first

        float s[8] = {0, 0, 0, 0, 0, 0, 0, 0};
        #pragma unroll
        for (int d = 0; d < 16; ++d) {
            const auto p0 = __builtin_amdgcn_cvt_pk_f32_fp8(vv[d].x, false);
            const auto p1 = __builtin_amdgcn_cvt_pk_f32_fp8(vv[d].x, true);
            const auto p2 = __builtin_amdgcn_cvt_pk_f32_fp8(vv[d].y, false);
            const auto p3 = __builtin_amdgcn_cvt_pk_f32_fp8(vv[d].y, true);
            s[0] += p0[0]; s[1] += p0[1]; s[2] += p1[0]; s[3] += p1[1];
            s[4] += p2[0]; s[5] += p2[1]; s[6] += p3[0]; s[7] += p3[1];
        }
        float h[8];
        #pragma unroll
        for (int j = 0; j < 8; ++j)
            h[j] = fmaxf(fmaf(s[j], inv, bf2f((ushort)q[j])), 0.f);
        uint4 u;
        u.x = cvtpk(h[0], h[1]);
        u.y = cvtpk(h[2], h[3]);
        u.z = cvtpk(h[4], h[5]);
        u.w = cvtpk(h[6], h[7]);
        *(uint4*)(hs + swz16(r, sl * 16)) = u;
    }
    __syncthreads();

    // Phase B: 4 waves; wave w -> local rows w*32 .. w*32+31 (1 frag)
    const int lane = t & 63;
    const int w = t >> 6;
    const int rl = w * 32;

    f32x16 acc = {0,0,0,0,0,0,0,0,0,0,0,0,0,0,0,0};
    #pragma unroll
    for (int kk = 0; kk < 8; ++kk) {
        const int kb = kk * 32 + (lane >> 5) * 16;
        const s16x8 a = *(const s16x8*)(hs + swz16(rl + (lane & 31), kb));
        const s16x8 b = *(const s16x8*)(WF2 + (size_t)(kk * 64 + lane) * 8);
        acc = __builtin_amdgcn_mfma_f32_32x32x16_bf16(a, b, acc, 0, 0, 0);
    }

    const int col = lane & 31;
    const int crow4 = 4 * (lane >> 5);
    #pragma unroll
    for (int g = 0; g < 16; g += 2) {
        const uint pk = cvtpk(acc[g], acc[g + 1]);
        const int row = node0 + rl + (g & 3) + 8 * (g >> 2) + crow4;
        if (row < NN)     STb[(size_t)row * 32 + col] = (ushort)pk;
        if (row + 1 < NN) STb[(size_t)(row + 1) * 32 + col] = (ushort)(pk >> 16);
    }
}

// ---------------------------------------------------------------------------
// Final: out[b][j] = S[node_b][j] + (1/16)*sum_d T[nbr(node_b,d)][j]
// One thread per (b, col-pair): dword gathers, float2 stores.
// ---------------------------------------------------------------------------
__global__ __launch_bounds__(256)
void final_out(const int* __restrict__ nodes, const int* __restrict__ nidx,
               const ushort* __restrict__ STb, float* __restrict__ out) {
    const int g = blockIdx.x * 256 + threadIdx.x;
    if (g >= NB * NC / 2) return;
    const int b = g >> 3;
    const int jp = g & 7;
    const int node = nodes[b];
    const uint sv = *(const uint*)(STb + (size_t)node * 32 + jp * 2);
    const int* nb = nidx + (size_t)node * DEG;
    float a0 = 0.f, a1 = 0.f;
    #pragma unroll
    for (int d = 0; d < DEG; ++d) {
        const uint v = *(const uint*)(STb + (size_t)nb[d] * 32 + 16 + jp * 2);
        a0 += bf2f((ushort)v);
        a1 += bf2f((ushort)(v >> 16));
    }
    float2 o;
    o.x = fmaf(a0, 1.0f / 16.0f, bf2f((ushort)sv));
    o.y = fmaf(a1, 1.0f / 16.0f, bf2f((ushort)(sv >> 16)));
    *(float2*)(out + (size_t)b * 16 + jp * 2) = o;
}

extern "C" void kernel_launch(void* const* d_in, const int* in_sizes, int n_in,
                              void* d_out, int out_size, void* d_ws, size_t ws_size,
                              hipStream_t stream) {
    const int* nodes = (const int*)d_in[0];
    const int* nidx  = (const int*)d_in[1];
    const float* X   = (const float*)d_in[2];
    const float* W1  = (const float*)d_in[3];
    const float* W2  = (const float*)d_in[4];
    float* out = (float*)d_out;

    // ws: Qb bf16 25.6MB | Pf fp8 12.8MB | STb bf16 6.4MB | WFh 64KB | WF2 8KB
    ushort* Qb = (ushort*)d_ws;
    unsigned char* Pf = (unsigned char*)(Qb + (size_t)NN * HID);
    ushort* STb = (ushort*)(Pf + (size_t)NN * HID);
    ushort* WFh = STb + (size_t)NN * 32;
    ushort* WF2 = WFh + 64 * 64 * 8;

    wf_prep<<<18, 256, 0, stream>>>(W1, W2, WFh, WF2);
    gemm1<<<782, 256, 0, stream>>>(X, WFh, Qb, Pf);
    agg_gemm2<<<782, 256, 0, stream>>>(nidx, Pf, Qb, WF2, STb);
    final_out<<<313, 256, 0, stream>>>(nodes, nidx, STb, out);
}

// Round 7
// 82.000 us; speedup vs baseline: 1.4000x; 1.1205x over previous
//
#include <hip/hip_runtime.h>
#include <hip/hip_bf16.h>

#define NN 100000
#define DEG 16
#define NF 128
#define HID 128
#define NC 16
#define NB 10000

typedef float f32x16 __attribute__((ext_vector_type(16)));
typedef short s16x8 __attribute__((ext_vector_type(8)));

__device__ __forceinline__ ushort f2bf(float f) {   // RNE (prep kernel only)
    unsigned u = __builtin_bit_cast(unsigned, f);
    return (ushort)((u + 0x7FFFu + ((u >> 16) & 1u)) >> 16);
}
__device__ __forceinline__ float bf2f(ushort h) {
    return __builtin_bit_cast(float, (unsigned)h << 16);
}
// HW packed fp32->bf16 RNE: dst = {lo: cvt(a), hi: cvt(b)}
__device__ __forceinline__ uint cvtpk(float a, float b) {
    uint r;
    asm("v_cvt_pk_bf16_f32 %0, %1, %2" : "=v"(r) : "v"(a), "v"(b));
    return r;
}
__device__ __forceinline__ s16x8 pack8(float4 a, float4 b) {
    uint4 u;
    u.x = cvtpk(a.x, a.y);
    u.y = cvtpk(a.z, a.w);
    u.z = cvtpk(b.x, b.y);
    u.w = cvtpk(b.z, b.w);
    return __builtin_bit_cast(s16x8, u);
}
// XOR swizzle within a 256B LDS row: 16 slots of 16B (T2, conflict-free b128)
__device__ __forceinline__ int swz16(int row, int bo) {
    return row * 256 + (bo ^ ((row & 15) << 4));
}

// ---------------------------------------------------------------------------
// Prep: W1 -> bf16 MFMA B-fragments WFh; W2 -> WF2.
// WFh frag (c,kk): lane l holds Wb[c*32+(l&31)][kk*16+(l>>5)*8 .. +8]
//   Wb[j][k] = j<128 ? W1[j][k] : W1[j-128][128+k]
// WF2 frag (kk):   lane l holds W2b[(l&31)][kk*16+(l>>5)*8 .. +8]
// ---------------------------------------------------------------------------
__global__ __launch_bounds__(256)
void wf_prep(const float* __restrict__ W1, const float* __restrict__ W2,
             ushort* __restrict__ WFh, ushort* __restrict__ WF2) {
    const int t = blockIdx.x * 256 + threadIdx.x;
    if (t >= 72 * 64) return;
    const int frag = t >> 6;
    const int lane = t & 63;
    const int k0 = (frag & 7) * 16 + (lane >> 5) * 8;

    if (frag < 64) {
        const int vcol = (frag >> 3) * 32 + (lane & 31);
        const float* src = (vcol < 128) ? W1 + (size_t)vcol * 256
                                        : W1 + (size_t)(vcol - 128) * 256 + 128;
        ushort hh[8];
        #pragma unroll
        for (int j = 0; j < 8; ++j) hh[j] = f2bf(src[k0 + j]);
        *(uint4*)(WFh + (size_t)t * 8) = *(const uint4*)hh;
    } else {
        const int vcol = lane & 31;
        const float* src = (vcol < 16) ? W2 + (size_t)vcol * 256
                                       : W2 + (size_t)(vcol - 16) * 256 + 128;
        ushort hh[8];
        #pragma unroll
        for (int j = 0; j < 8; ++j) hh[j] = f2bf(src[k0 + j]);
        *(uint4*)(WF2 + (size_t)((frag - 64) * 64 + lane) * 8) = *(const uint4*)hh;
    }
}

// ---------------------------------------------------------------------------
// GEMM1 (no LDS): 512 threads, block = 128 rows x 256 cols, K=128.
// 8 waves: wm = w&3 (32-row frag), wn = w>>2 (col half of 128).
// Wave's whole A-panel (16 float4) issued up-front (one mem round-trip),
// then pure {L2-hot B load + MFMA} inner loop. acc = 4 frags = 64 AGPR.
// Out: cols<128 -> Qb (bf16), cols>=128 -> Pf (fp8 e4m3).
// ---------------------------------------------------------------------------
__global__ __launch_bounds__(512)
void gemm1(const float* __restrict__ X, const ushort* __restrict__ WFh,
           ushort* __restrict__ Qb, unsigned char* __restrict__ Pf) {
    const int t = threadIdx.x;
    const int lane = t & 63;
    const int w = t >> 6;          // 0..7
    const int wm = w & 3;          // row frag
    const int wn = w >> 2;         // col half
    const int row0 = blockIdx.x * 128;

    int r = row0 + wm * 32 + (lane & 31);
    if (r > NN - 1) r = NN - 1;
    const float* ap = X + (size_t)r * NF + (lane >> 5) * 8;

    // ---- one-shot A panel load (16 independent dwordx4)
    float4 t0[8], t1[8];
    #pragma unroll
    for (int kk = 0; kk < 8; ++kk) {
        t0[kk] = *(const float4*)(ap + kk * 16);
        t1[kk] = *(const float4*)(ap + kk * 16 + 4);
    }
    __builtin_amdgcn_sched_barrier(0);
    s16x8 a[8];
    #pragma unroll
    for (int kk = 0; kk < 8; ++kk) a[kk] = pack8(t0[kk], t1[kk]);

    f32x16 acc[4];
    #pragma unroll
    for (int n = 0; n < 4; ++n)
        acc[n] = (f32x16){0,0,0,0,0,0,0,0,0,0,0,0,0,0,0,0};

    #pragma unroll
    for (int kk = 0; kk < 8; ++kk) {
        #pragma unroll
        for (int n = 0; n < 4; ++n) {
            const int cf = wn * 4 + n;
            const s16x8 b = *(const s16x8*)(WFh + (size_t)((cf * 8 + kk) * 64 + lane) * 8);
            acc[n] = __builtin_amdgcn_mfma_f32_32x32x16_bf16(a[kk], b, acc[n], 0, 0, 0);
        }
    }

    // ---- epilogue: C/D layout col=lane&31, row=(g&3)+8*(g>>2)+4*(lane>>5)
    const int ccol = lane & 31;
    const int crow4 = 4 * (lane >> 5);
    if (wn == 0) {
        #pragma unroll
        for (int n = 0; n < 4; ++n) {
            const int col = n * 32 + ccol;
            #pragma unroll
            for (int g = 0; g < 16; g += 2) {
                const uint pk = cvtpk(acc[n][g], acc[n][g + 1]);
                const int row = row0 + wm * 32 + (g & 3) + 8 * (g >> 2) + crow4;
                if (row < NN)     Qb[(size_t)row * HID + col] = (ushort)pk;
                if (row + 1 < NN) Qb[(size_t)(row + 1) * HID + col] = (ushort)(pk >> 16);
            }
        }
    } else {
        #pragma unroll
        for (int n = 0; n < 4; ++n) {
            const int pc = n * 32 + ccol;
            #pragma unroll
            for (int g = 0; g < 16; g += 2) {
                const uint pk = __builtin_amdgcn_cvt_pk_fp8_f32(
                    acc[n][g], acc[n][g + 1], 0, false);
                const int row = row0 + wm * 32 + (g & 3) + 8 * (g >> 2) + crow4;
                if (row < NN)     Pf[(size_t)row * HID + pc] = (unsigned char)(pk & 0xff);
                if (row + 1 < NN) Pf[(size_t)(row + 1) * HID + pc] = (unsigned char)((pk >> 8) & 0xff);
            }
        }
    }
}

// ---------------------------------------------------------------------------
// Fused aggregate + GEMM2. Block = 128 nodes, 32KB LDS.
// Phase A: h1[n] = relu(Qb[n] + mean_d Pf[nbr(n,d)]) -> swizzled LDS (bf16).
//   8 lanes/node, 16B (dwordx4) per lane per neighbor row; all 16 gathers
//   issued before decode (sched_barrier) for max MLP.
// Phase B: ST = h1 @ W2frag (MFMA from LDS) -> STb (bf16).
// ---------------------------------------------------------------------------
__global__ __launch_bounds__(256, 2)
void agg_gemm2(const int* __restrict__ nidx, const unsigned char* __restrict__ Pf,
               const ushort* __restrict__ Qb, const ushort* __restrict__ WF2,
               ushort* __restrict__ STb) {
    __shared__ char hs[128 * 256];  // 32KB: 128 rows x 128 bf16, swizzled
    const int t = threadIdx.x;
    const int node0 = blockIdx.x * 128;
    const int sl = t & 7;    // 16B fp8-slice of a row (16 elems)
    const int ng = t >> 3;   // node slot 0..31

    const float inv = 1.0f / 16.0f;
    #pragma unroll 1
    for (int it = 0; it < 4; ++it) {
        const int r = ng + it * 32;          // local row 0..127
        int node = node0 + r;
        if (node > NN - 1) node = NN - 1;
        const int2 myn = *(const int2*)(nidx + (size_t)node * DEG + sl * 2);

        uint4 vv[16];
        #pragma unroll
        for (int d = 0; d < 16; ++d) {
            const uint id = (uint)__shfl((d & 1) ? myn.y : myn.x, d >> 1, 8);
            vv[d] = *(const uint4*)(Pf + (size_t)id * HID + sl * 16);
        }
        __builtin_amdgcn_sched_barrier(0);   // all 16 gathers in flight first

        float s[16];
        #pragma unroll
        for (int j = 0; j < 16; ++j) s[j] = 0.f;
        #pragma unroll
        for (int d = 0; d < 16; ++d) {
            const uint wd[4] = {vv[d].x, vv[d].y, vv[d].z, vv[d].w};
            #pragma unroll
            for (int q = 0; q < 4; ++q) {
                const auto plo = __builtin_amdgcn_cvt_pk_f32_fp8(wd[q], false);
                const auto phi = __builtin_amdgcn_cvt_pk_f32_fp8(wd[q], true);
                s[q * 4 + 0] += plo[0]; s[q * 4 + 1] += plo[1];
                s[q * 4 + 2] += phi[0]; s[q * 4 + 3] += phi[1];
            }
        }

        const ushort* qp = Qb + (size_t)node * HID + sl * 16;
        const s16x8 q0 = *(const s16x8*)qp;
        const s16x8 q1 = *(const s16x8*)(qp + 8);
        float h[16];
        #pragma unroll
        for (int j = 0; j < 8; ++j) {
            h[j]     = fmaxf(fmaf(s[j],     inv, bf2f((ushort)q0[j])), 0.f);
            h[j + 8] = fmaxf(fmaf(s[j + 8], inv, bf2f((ushort)q1[j])), 0.f);
        }
        uint4 u0, u1;
        u0.x = cvtpk(h[0], h[1]);   u0.y = cvtpk(h[2], h[3]);
        u0.z = cvtpk(h[4], h[5]);   u0.w = cvtpk(h[6], h[7]);
        u1.x = cvtpk(h[8], h[9]);   u1.y = cvtpk(h[10], h[11]);
        u1.z = cvtpk(h[12], h[13]); u1.w = cvtpk(h[14], h[15]);
        *(uint4*)(hs + swz16(r, sl * 32)) = u0;
        *(uint4*)(hs + swz16(r, sl * 32 + 16)) = u1;
    }
    __syncthreads();

    // Phase B: 4 waves; wave w -> local rows w*32 .. w*32+31 (1 frag)
    const int lane = t & 63;
    const int w = t >> 6;
    const int rl = w * 32;

    f32x16 acc = {0,0,0,0,0,0,0,0,0,0,0,0,0,0,0,0};
    #pragma unroll
    for (int kk = 0; kk < 8; ++kk) {
        const int kb = kk * 32 + (lane >> 5) * 16;
        const s16x8 a = *(const s16x8*)(hs + swz16(rl + (lane & 31), kb));
        const s16x8 b = *(const s16x8*)(WF2 + (size_t)(kk * 64 + lane) * 8);
        acc = __builtin_amdgcn_mfma_f32_32x32x16_bf16(a, b, acc, 0, 0, 0);
    }

    const int col = lane & 31;
    const int crow4 = 4 * (lane >> 5);
    #pragma unroll
    for (int g = 0; g < 16; g += 2) {
        const uint pk = cvtpk(acc[g], acc[g + 1]);
        const int row = node0 + rl + (g & 3) + 8 * (g >> 2) + crow4;
        if (row < NN)     STb[(size_t)row * 32 + col] = (ushort)pk;
        if (row + 1 < NN) STb[(size_t)(row + 1) * 32 + col] = (ushort)(pk >> 16);
    }
}

// ---------------------------------------------------------------------------
// Final: out[b][j] = S[node_b][j] + (1/16)*sum_d T[nbr(node_b,d)][j]
// One thread per (b, col-pair): dword gathers, float2 stores.
// ---------------------------------------------------------------------------
__global__ __launch_bounds__(256)
void final_out(const int* __restrict__ nodes, const int* __restrict__ nidx,
               const ushort* __restrict__ STb, float* __restrict__ out) {
    const int g = blockIdx.x * 256 + threadIdx.x;
    if (g >= NB * NC / 2) return;
    const int b = g >> 3;
    const int jp = g & 7;
    const int node = nodes[b];
    const uint sv = *(const uint*)(STb + (size_t)node * 32 + jp * 2);
    const int* nb = nidx + (size_t)node * DEG;
    float a0 = 0.f, a1 = 0.f;
    #pragma unroll
    for (int d = 0; d < DEG; ++d) {
        const uint v = *(const uint*)(STb + (size_t)nb[d] * 32 + 16 + jp * 2);
        a0 += bf2f((ushort)v);
        a1 += bf2f((ushort)(v >> 16));
    }
    float2 o;
    o.x = fmaf(a0, 1.0f / 16.0f, bf2f((ushort)sv));
    o.y = fmaf(a1, 1.0f / 16.0f, bf2f((ushort)(sv >> 16)));
    *(float2*)(out + (size_t)b * 16 + jp * 2) = o;
}

extern "C" void kernel_launch(void* const* d_in, const int* in_sizes, int n_in,
                              void* d_out, int out_size, void* d_ws, size_t ws_size,
                              hipStream_t stream) {
    const int* nodes = (const int*)d_in[0];
    const int* nidx  = (const int*)d_in[1];
    const float* X   = (const float*)d_in[2];
    const float* W1  = (const float*)d_in[3];
    const float* W2  = (const float*)d_in[4];
    float* out = (float*)d_out;

    // ws: Qb bf16 25.6MB | Pf fp8 12.8MB | STb bf16 6.4MB | WFh 64KB | WF2 8KB
    ushort* Qb = (ushort*)d_ws;
    unsigned char* Pf = (unsigned char*)(Qb + (size_t)NN * HID);
    ushort* STb = (ushort*)(Pf + (size_t)NN * HID);
    ushort* WFh = STb + (size_t)NN * 32;
    ushort* WF2 = WFh + 64 * 64 * 8;

    wf_prep<<<18, 256, 0, stream>>>(W1, W2, WFh, WF2);
    gemm1<<<782, 512, 0, stream>>>(X, WFh, Qb, Pf);
    agg_gemm2<<<782, 256, 0, stream>>>(nidx, Pf, Qb, WF2, STb);
    final_out<<<313, 256, 0, stream>>>(nodes, nidx, STb, out);
}